// Round 1
// baseline (38.047 us; speedup 1.0000x reference)
//
#include <hip/hip_runtime.h>

#define EPS 1e-8f

// One wave64 per batch (N=32 items, 1024 ordered pairs).
// Lane l, iter t -> pair (i = 2t + (l>>5), j = l&31).
// j-side operands are lane-resident; i-side needs 2 shuffles/iter.
__global__ __launch_bounds__(256) void ranknet_partial_kernel(
    const float* __restrict__ scores,
    const int*   __restrict__ rankings,
    const int*   __restrict__ mask,
    float2*      __restrict__ partials)
{
    const int lane = threadIdx.x & 63;
    const int wave = threadIdx.x >> 6;
    const int b    = blockIdx.x * 4 + wave;   // grid sized so b < B always

    const int item = lane & 31;
    const int idx  = b * 32 + item;
    const float s  = scores[idx];
    const int   r  = rankings[idx];
    const int   m  = mask[idx];
    // rr==0 encodes "invalid item" (valid requires rank>0 anyway)
    const int   rr = (m != 0 && r > 0) ? r : 0;

    const float sj = s;
    const int   rj = rr;
    const int   hi = lane >> 5;

    float lsum = 0.0f;
    float lcnt = 0.0f;

    #pragma unroll
    for (int t = 0; t < 16; ++t) {
        const int   i  = 2 * t + hi;
        const float si = __shfl(s, i);     // lanes 0..31 hold items 0..31
        const int   ri = __shfl(rr, i);

        const float x   = si - sj;
        const float sig = 1.0f / (1.0f + __expf(-x));
        const float arg = (ri < rj) ? (sig + EPS) : (1.0f - sig + EPS);
        const bool  pv  = (ri > 0) & (rj > 0) & (ri != rj);
        if (pv) {
            lsum -= __logf(arg);
            lcnt += 1.0f;
        }
    }

    // wave64 butterfly reduction
    #pragma unroll
    for (int off = 32; off > 0; off >>= 1) {
        lsum += __shfl_xor(lsum, off);
        lcnt += __shfl_xor(lcnt, off);
    }

    __shared__ float2 wpart[4];
    if (lane == 0) {
        const float pb  = (lcnt > 0.0f) ? (lsum / lcnt) : 0.0f;
        const float has = (lcnt > 0.0f) ? 1.0f : 0.0f;
        wpart[wave] = make_float2(pb, has);
    }
    __syncthreads();
    if (threadIdx.x == 0) {
        float ps = 0.0f, pc = 0.0f;
        #pragma unroll
        for (int w = 0; w < 4; ++w) { ps += wpart[w].x; pc += wpart[w].y; }
        partials[blockIdx.x] = make_float2(ps, pc);
    }
}

__global__ __launch_bounds__(1024) void ranknet_finalize_kernel(
    const float2* __restrict__ partials, int n, float* __restrict__ out)
{
    float s = 0.0f, c = 0.0f;
    for (int i = threadIdx.x; i < n; i += 1024) {
        const float2 p = partials[i];
        s += p.x;
        c += p.y;
    }
    #pragma unroll
    for (int off = 32; off > 0; off >>= 1) {
        s += __shfl_xor(s, off);
        c += __shfl_xor(c, off);
    }
    __shared__ float2 wsum[16];
    const int wave = threadIdx.x >> 6;
    const int lane = threadIdx.x & 63;
    if (lane == 0) wsum[wave] = make_float2(s, c);
    __syncthreads();
    if (threadIdx.x == 0) {
        float ts = 0.0f, tc = 0.0f;
        #pragma unroll
        for (int w = 0; w < 16; ++w) { ts += wsum[w].x; tc += wsum[w].y; }
        out[0] = (tc > 0.0f) ? (ts / tc) : 0.0f;
    }
}

extern "C" void kernel_launch(void* const* d_in, const int* in_sizes, int n_in,
                              void* d_out, int out_size, void* d_ws, size_t ws_size,
                              hipStream_t stream) {
    const float* scores   = (const float*)d_in[0];
    const int*   rankings = (const int*)d_in[1];
    const int*   mask     = (const int*)d_in[2];
    float*       out      = (float*)d_out;

    const int B       = in_sizes[0] / 32;   // 32768
    const int nblocks = (B + 3) / 4;        // 8192 blocks x 4 waves = 1 batch/wave

    float2* partials = (float2*)d_ws;       // 8192 * 8B = 64 KB, every slot written

    ranknet_partial_kernel<<<nblocks, 256, 0, stream>>>(scores, rankings, mask, partials);
    ranknet_finalize_kernel<<<1, 1024, 0, stream>>>(partials, nblocks, out);
}

// Round 2
// 20.782 us; speedup vs baseline: 1.8308x; 1.8308x over previous
//
#include <hip/hip_runtime.h>

// One wave64 handles TWO batches (lanes 0-31 = batch 2w, lanes 32-63 = batch 2w+1).
// Unordered pairs via rotation: iter t pairs item j with item (j+t)%32, t=1..16.
// t=16 generates each antipodal pair from both ends -> weight 0.5.
// loss(i,j) == loss(j,i) exactly (sigma(-x) = 1-sigma(x)), so the unordered mean
// equals the reference's ordered mean.
__global__ __launch_bounds__(256) void ranknet_partial_kernel(
    const float* __restrict__ scores,
    const int*   __restrict__ rankings,
    const int*   __restrict__ mask,
    float2*      __restrict__ partials)
{
    const int tid  = blockIdx.x * 256 + threadIdx.x;  // global item slot (coalesced)
    const int lane = threadIdx.x & 63;
    const int wave = threadIdx.x >> 6;

    const float s = scores[tid];
    const int   r = rankings[tid];
    const int   m = mask[tid];
    const int   rj = (m != 0 && r > 0) ? r : 0;       // 0 encodes invalid

    const int item = lane & 31;
    const int half = lane & 32;                       // batch selector within wave

    float lsum = 0.0f;
    float lcnt = 0.0f;

    #pragma unroll
    for (int t = 1; t <= 16; ++t) {
        const int   src = half | ((item + t) & 31);
        const float si  = __shfl(s,  src);
        const int   ri  = __shfl(rj, src);

        const float x = si - s;                       // s_i - s_j
        const bool  p = (ri < rj);
        const float y = p ? -x : x;                   // loss = softplus(y)
        const float e  = __expf(-fabsf(y));
        const float sp = fmaxf(y, 0.0f) + __logf(1.0f + e);

        const bool valid = (ri > 0) & (rj > 0) & (ri != rj);
        const float w = (t == 16) ? 0.5f : 1.0f;
        lsum += valid ? w * sp : 0.0f;
        lcnt += valid ? w : 0.0f;
    }

    // butterfly within each 32-lane half (per-batch reduction)
    #pragma unroll
    for (int off = 16; off > 0; off >>= 1) {
        lsum += __shfl_xor(lsum, off);
        lcnt += __shfl_xor(lcnt, off);
    }
    float pb  = (lcnt > 0.0f) ? (lsum / lcnt) : 0.0f; // per-batch mean loss
    float has = (lcnt > 0.0f) ? 1.0f : 0.0f;
    pb  += __shfl_xor(pb, 32);                        // combine the wave's 2 batches
    has += __shfl_xor(has, 32);

    __shared__ float2 wpart[4];
    if (lane == 0) wpart[wave] = make_float2(pb, has);
    __syncthreads();
    if (threadIdx.x == 0) {
        float ps = 0.0f, pc = 0.0f;
        #pragma unroll
        for (int w2 = 0; w2 < 4; ++w2) { ps += wpart[w2].x; pc += wpart[w2].y; }
        partials[blockIdx.x] = make_float2(ps, pc);
    }
}

__global__ __launch_bounds__(1024) void ranknet_finalize_kernel(
    const float2* __restrict__ partials, int n, float* __restrict__ out)
{
    float s = 0.0f, c = 0.0f;
    for (int i = threadIdx.x; i < n; i += 1024) {
        const float2 p = partials[i];
        s += p.x;
        c += p.y;
    }
    #pragma unroll
    for (int off = 32; off > 0; off >>= 1) {
        s += __shfl_xor(s, off);
        c += __shfl_xor(c, off);
    }
    __shared__ float2 wsum[16];
    const int wave = threadIdx.x >> 6;
    const int lane = threadIdx.x & 63;
    if (lane == 0) wsum[wave] = make_float2(s, c);
    __syncthreads();
    if (threadIdx.x == 0) {
        float ts = 0.0f, tc = 0.0f;
        #pragma unroll
        for (int w = 0; w < 16; ++w) { ts += wsum[w].x; tc += wsum[w].y; }
        out[0] = (tc > 0.0f) ? (ts / tc) : 0.0f;
    }
}

extern "C" void kernel_launch(void* const* d_in, const int* in_sizes, int n_in,
                              void* d_out, int out_size, void* d_ws, size_t ws_size,
                              hipStream_t stream) {
    const float* scores   = (const float*)d_in[0];
    const int*   rankings = (const int*)d_in[1];
    const int*   mask     = (const int*)d_in[2];
    float*       out      = (float*)d_out;

    const int total   = in_sizes[0];        // B * 32
    const int nblocks = total / 256;        // 4096: 8 batches per block

    float2* partials = (float2*)d_ws;       // 4096 * 8B = 32 KB, every slot written

    ranknet_partial_kernel<<<nblocks, 256, 0, stream>>>(scores, rankings, mask, partials);
    ranknet_finalize_kernel<<<1, 1024, 0, stream>>>(partials, nblocks, out);
}

// Round 3
// 20.497 us; speedup vs baseline: 1.8562x; 1.0139x over previous
//
#include <hip/hip_runtime.h>

// One wave64 handles TWO batches (lanes 0-31 = batch A, lanes 32-63 = batch B).
// Unordered pairs via rotation t=1..16 (t=16 antipodal pairs weighted 0.5).
// Rank (5 bits, 0 = invalid) is packed into the score's low mantissa bits so
// each rotation needs a single __shfl; perturbation <= 4e-6 per score.
__global__ __launch_bounds__(256) void ranknet_partial_kernel(
    const float* __restrict__ scores,
    const int*   __restrict__ rankings,
    const int*   __restrict__ mask,
    float2*      __restrict__ partials)
{
    const int tid  = blockIdx.x * 256 + threadIdx.x;  // global item slot (coalesced)
    const int lane = threadIdx.x & 63;
    const int wave = threadIdx.x >> 6;

    const float s = scores[tid];
    const int   r = rankings[tid];
    const int   m = mask[tid];
    const int   rr = (m != 0 && r > 0) ? r : 0;       // 0 encodes invalid

    // pack rank into score mantissa LSBs
    const unsigned su = (__float_as_uint(s) & ~31u) | (unsigned)rr;
    const float sj = __uint_as_float(su);
    const int   rj = rr;

    const int item = lane & 31;
    const int half = lane & 32;

    // Phase 1: all shuffles up front, results pinned in registers
    unsigned pk[16];
    #pragma unroll
    for (int t = 1; t <= 16; ++t)
        pk[t - 1] = __shfl(su, half | ((item + t) & 31));

    // Phase 2: pure-register compute
    float lsum = 0.0f;
    float lcnt = 0.0f;
    #pragma unroll
    for (int t = 1; t <= 16; ++t) {
        const unsigned pu = pk[t - 1];
        const int   ri = (int)(pu & 31u);
        const float si = __uint_as_float(pu);

        const float x  = si - sj;                     // s_i - s_j
        const float y  = (ri < rj) ? -x : x;          // loss = softplus(y)
        const float e  = __expf(-fabsf(y));
        const float sp = fmaxf(y, 0.0f) + __logf(1.0f + e);

        const bool valid = (ri != 0) & (rj != 0) & (ri != rj);
        const float w  = (t == 16) ? 0.5f : 1.0f;
        const float ws = valid ? w : 0.0f;
        lsum = fmaf(ws, sp, lsum);
        lcnt += ws;
    }

    // butterfly within each 32-lane half (per-batch reduction)
    #pragma unroll
    for (int off = 16; off > 0; off >>= 1) {
        lsum += __shfl_xor(lsum, off);
        lcnt += __shfl_xor(lcnt, off);
    }
    float pb  = (lcnt > 0.0f) ? (lsum / lcnt) : 0.0f; // per-batch mean loss
    float has = (lcnt > 0.0f) ? 1.0f : 0.0f;
    pb  += __shfl_xor(pb, 32);                        // combine the wave's 2 batches
    has += __shfl_xor(has, 32);

    __shared__ float2 wpart[4];
    if (lane == 0) wpart[wave] = make_float2(pb, has);
    __syncthreads();
    if (threadIdx.x == 0) {
        float ps = 0.0f, pc = 0.0f;
        #pragma unroll
        for (int w2 = 0; w2 < 4; ++w2) { ps += wpart[w2].x; pc += wpart[w2].y; }
        partials[blockIdx.x] = make_float2(ps, pc);
    }
}

__global__ __launch_bounds__(1024) void ranknet_finalize_kernel(
    const float2* __restrict__ partials, int n, float* __restrict__ out)
{
    float s = 0.0f, c = 0.0f;
    for (int i = threadIdx.x; i < n; i += 1024) {
        const float2 p = partials[i];
        s += p.x;
        c += p.y;
    }
    #pragma unroll
    for (int off = 32; off > 0; off >>= 1) {
        s += __shfl_xor(s, off);
        c += __shfl_xor(c, off);
    }
    __shared__ float2 wsum[16];
    const int wave = threadIdx.x >> 6;
    const int lane = threadIdx.x & 63;
    if (lane == 0) wsum[wave] = make_float2(s, c);
    __syncthreads();
    if (threadIdx.x == 0) {
        float ts = 0.0f, tc = 0.0f;
        #pragma unroll
        for (int w = 0; w < 16; ++w) { ts += wsum[w].x; tc += wsum[w].y; }
        out[0] = (tc > 0.0f) ? (ts / tc) : 0.0f;
    }
}

extern "C" void kernel_launch(void* const* d_in, const int* in_sizes, int n_in,
                              void* d_out, int out_size, void* d_ws, size_t ws_size,
                              hipStream_t stream) {
    const float* scores   = (const float*)d_in[0];
    const int*   rankings = (const int*)d_in[1];
    const int*   mask     = (const int*)d_in[2];
    float*       out      = (float*)d_out;

    const int total   = in_sizes[0];        // B * 32
    const int nblocks = total / 256;        // 4096: 8 batches per block

    float2* partials = (float2*)d_ws;       // 4096 * 8B = 32 KB, every slot written

    ranknet_partial_kernel<<<nblocks, 256, 0, stream>>>(scores, rankings, mask, partials);
    ranknet_finalize_kernel<<<1, 1024, 0, stream>>>(partials, nblocks, out);
}